// Round 6
// baseline (575.806 us; speedup 1.0000x reference)
//
#include <hip/hip_runtime.h>
#include <stdint.h>

#define SEQL 2521
#define LPAD 2560
#define NB 2
#define NH 16
#define HD 128
#define CD 2048
#define KD 2048

typedef float f32x4 __attribute__((ext_vector_type(4)));
typedef __bf16 bf16x8 __attribute__((ext_vector_type(8)));
typedef unsigned short u16x8 __attribute__((ext_vector_type(8)));

static __device__ __forceinline__ unsigned short bf16c(float f){
  __bf16 h = (__bf16)f;
  return __builtin_bit_cast(unsigned short, h);
}
static __device__ __forceinline__ float bf2f(unsigned short s){
  union { unsigned u; float f; } v; v.u = ((unsigned)s) << 16; return v.f;
}
static __device__ __forceinline__ bf16x8 asbf(u16x8 v){ return __builtin_bit_cast(bf16x8, v); }

typedef const __attribute__((address_space(1))) unsigned int* gas1_t;
typedef __attribute__((address_space(3))) unsigned int* las3_t;
static __device__ __forceinline__ void glds16(const void* g, void* l){
  __builtin_amdgcn_global_load_lds((gas1_t)g, (las3_t)l, 16, 0, 0);
}

// ---------------------------------------------------------------- prep
__global__ __launch_bounds__(256) void prep_kernel(
    const float* __restrict__ x, const float* __restrict__ wqkv, const float* __restrict__ projw,
    unsigned short* __restrict__ xb, unsigned short* __restrict__ wb, unsigned short* __restrict__ pw)
{
  const int NX = (NB*LPAD*CD)/4;
  const int NW = (3*CD*CD)/4;
  const int NPj = (CD*CD)/4;
  const int total = NX + NW + NPj;
  for (int v = blockIdx.x*256 + threadIdx.x; v < total; v += gridDim.x*256){
    if (v < NX){
      int e = v << 2;
      int row = e >> 11, col = e & 2047;
      int b = (row >= LPAD) ? 1 : 0;
      int l = row - b*LPAD;
      ushort4 o;
      if (l < SEQL){
        const float4 f = *(const float4*)(x + (((long)(b*SEQL + l)) << 11) + col);
        o.x = bf16c(f.x); o.y = bf16c(f.y); o.z = bf16c(f.z); o.w = bf16c(f.w);
      } else { o.x = 0; o.y = 0; o.z = 0; o.w = 0; }
      *(ushort4*)(xb + e) = o;
    } else if (v < NX + NW){
      long i = (long)(v - NX) << 2;
      const float4 f = *(const float4*)(wqkv + i);
      ushort4 o; o.x=bf16c(f.x); o.y=bf16c(f.y); o.z=bf16c(f.z); o.w=bf16c(f.w);
      *(ushort4*)(wb + i) = o;
    } else {
      long i = (long)(v - NX - NW) << 2;
      const float4 f = *(const float4*)(projw + i);
      ushort4 o; o.x=bf16c(f.x); o.y=bf16c(f.y); o.z=bf16c(f.z); o.w=bf16c(f.w);
      *(ushort4*)(pw + i) = o;
    }
  }
}

// ---------------------------------------------------------------- 8-phase 256x256 GEMM core
static __device__ __forceinline__ void gemm8p(
    const unsigned short* __restrict__ A, const unsigned short* __restrict__ Bm,
    unsigned short* lds, int m0, int n0, f32x4 acc[8][4])
{
  const int tid = threadIdx.x;
  const int w = tid >> 6, lane = tid & 63;
  const int g = lane >> 4, lr = lane & 15;
  const int wm = w >> 2, wn = w & 3;
  const int xorv = (lr & 7) << 3;
  const int off0 = (g << 3) ^ xorv;
  const int arow = wm*128 + lr;
  const int brow = wn*64 + lr;

  auto stage = [&](int mat, int kt, int half, int buf){
    const unsigned short* G = mat ? Bm : A;
    const int base0 = mat ? n0 : m0;
    unsigned short* lb = lds + buf*32768 + mat*16384;
#pragma unroll
    for (int p = 0; p < 2; ++p){
      const int cb_ = (half<<10) + (p<<9) + (w<<6);
      const int c = cb_ + lane;
      const int row = c >> 3, cc = c & 7;
      glds16(G + (size_t)(base0 + row)*KD + (kt<<6) + ((cc ^ (row & 7)) << 3),
             lb + (cb_ << 3));
    }
  };
  auto rdA = [&](int buf, int i, int ks)->u16x8 {
    return *(const u16x8*)(lds + buf*32768 + (arow + i*16)*64 + (off0 ^ (ks<<5)));
  };
  auto rdB = [&](int buf, int j, int ks)->u16x8 {
    return *(const u16x8*)(lds + buf*32768 + 16384 + (brow + j*16)*64 + (off0 ^ (ks<<5)));
  };

  u16x8 bfr[4][2], af[2][2];
  auto mfma16 = [&](int q){
#pragma unroll
    for (int i2 = 0; i2 < 2; ++i2)
#pragma unroll
      for (int ks = 0; ks < 2; ++ks)
#pragma unroll
        for (int j = 0; j < 4; ++j)
          acc[2*q+i2][j] = __builtin_amdgcn_mfma_f32_16x16x32_bf16(
              asbf(af[i2][ks]), asbf(bfr[j][ks]), acc[2*q+i2][j], 0, 0, 0);
  };

#define PH_SYNC_MFMA(Q) \
    __builtin_amdgcn_s_barrier(); \
    asm volatile("s_waitcnt lgkmcnt(0)" ::: "memory"); \
    __builtin_amdgcn_s_setprio(1); mfma16(Q); __builtin_amdgcn_s_setprio(0);

  stage(0, 0, 0, 0); stage(0, 0, 1, 0);
  stage(1, 0, 0, 0); stage(1, 0, 1, 0);
  stage(1, 1, 0, 1); stage(1, 1, 1, 1);
  asm volatile("s_waitcnt vmcnt(4)" ::: "memory");
  __builtin_amdgcn_s_barrier();

  const int NI = KD >> 7;
  for (int it = 0; it < NI; ++it){
    const int kt = it << 1;
    const bool last = (it == NI-1);
#pragma unroll
    for (int j = 0; j < 4; ++j){ bfr[j][0]=rdB(0,j,0); bfr[j][1]=rdB(0,j,1); }
    af[0][0]=rdA(0,0,0); af[0][1]=rdA(0,0,1); af[1][0]=rdA(0,1,0); af[1][1]=rdA(0,1,1);
    stage(0, kt+1, 0, 1);
    PH_SYNC_MFMA(0)
    __builtin_amdgcn_s_barrier();

    af[0][0]=rdA(0,2,0); af[0][1]=rdA(0,2,1); af[1][0]=rdA(0,3,0); af[1][1]=rdA(0,3,1);
    stage(0, kt+1, 1, 1);
    PH_SYNC_MFMA(1)
    __builtin_amdgcn_s_barrier();

    af[0][0]=rdA(0,4,0); af[0][1]=rdA(0,4,1); af[1][0]=rdA(0,5,0); af[1][1]=rdA(0,5,1);
    if (!last) stage(1, kt+2, 0, 0);
    PH_SYNC_MFMA(2)
    __builtin_amdgcn_s_barrier();

    af[0][0]=rdA(0,6,0); af[0][1]=rdA(0,6,1); af[1][0]=rdA(0,7,0); af[1][1]=rdA(0,7,1);
    if (!last) stage(1, kt+2, 1, 0);
    PH_SYNC_MFMA(3)
    if (last) { asm volatile("s_waitcnt vmcnt(0)" ::: "memory"); }
    else      { asm volatile("s_waitcnt vmcnt(4)" ::: "memory"); }
    __builtin_amdgcn_s_barrier();

#pragma unroll
    for (int j = 0; j < 4; ++j){ bfr[j][0]=rdB(1,j,0); bfr[j][1]=rdB(1,j,1); }
    af[0][0]=rdA(1,0,0); af[0][1]=rdA(1,0,1); af[1][0]=rdA(1,1,0); af[1][1]=rdA(1,1,1);
    if (!last) stage(0, kt+2, 0, 0);
    PH_SYNC_MFMA(0)
    __builtin_amdgcn_s_barrier();

    af[0][0]=rdA(1,2,0); af[0][1]=rdA(1,2,1); af[1][0]=rdA(1,3,0); af[1][1]=rdA(1,3,1);
    if (!last) stage(0, kt+2, 1, 0);
    PH_SYNC_MFMA(1)
    __builtin_amdgcn_s_barrier();

    af[0][0]=rdA(1,4,0); af[0][1]=rdA(1,4,1); af[1][0]=rdA(1,5,0); af[1][1]=rdA(1,5,1);
    if (!last) stage(1, kt+3, 0, 1);
    PH_SYNC_MFMA(2)
    __builtin_amdgcn_s_barrier();

    af[0][0]=rdA(1,6,0); af[0][1]=rdA(1,6,1); af[1][0]=rdA(1,7,0); af[1][1]=rdA(1,7,1);
    if (!last) stage(1, kt+3, 1, 1);
    PH_SYNC_MFMA(3)
    if (last) { asm volatile("s_waitcnt vmcnt(0)" ::: "memory"); }
    else      { asm volatile("s_waitcnt vmcnt(4)" ::: "memory"); }
    __builtin_amdgcn_s_barrier();
  }
#undef PH_SYNC_MFMA
}

// ---------------------------------------------------------------- GEMM1: QKV
__global__ __launch_bounds__(512, 2) void gemm_qkv(
    const unsigned short* __restrict__ A, const unsigned short* __restrict__ W,
    const float* __restrict__ qb, const float* __restrict__ vb,
    unsigned short* __restrict__ qg, unsigned short* __restrict__ kg,
    unsigned short* __restrict__ vt)
{
  __shared__ __align__(16) unsigned short lds[65536];
  f32x4 acc[8][4] = {};
  const int bid = blockIdx.x;
  const int swz = (bid & 7)*60 + (bid >> 3);
  const int mt = swz / 24, ntt = swz % 24;
  const int m0 = mt << 8, n0 = ntt << 8;
  gemm8p(A, W, lds, m0, n0, acc);

  const int tid = threadIdx.x;
  const int w = tid >> 6, lane = tid & 63, g = lane >> 4, lr = lane & 15;
  const int wm = w >> 2, wn = w & 3;
  const int part = n0 >> 11;
  const int b = (m0 >= LPAD) ? 1 : 0;
  const int l0 = m0 - b*LPAD;
  const int colbase = (n0 & 2047) + wn*64;
#pragma unroll
  for (int i = 0; i < 8; ++i){
    const int mloc = wm*128 + i*16 + (g << 2);
#pragma unroll
    for (int j = 0; j < 4; ++j){
      const int col = colbase + j*16 + lr;
      const int hb = col >> 7, d = col & 127;
      const float bias = (part == 0) ? qb[col] : ((part == 2) ? vb[col] : 0.f);
      const f32x4 v = acc[i][j];
      if (part == 2){
        ushort4 o;
        o.x = bf16c(v[0] + bias); o.y = bf16c(v[1] + bias);
        o.z = bf16c(v[2] + bias); o.w = bf16c(v[3] + bias);
        *(ushort4*)(vt + ((size_t)((b*NH + hb)*HD + d))*LPAD + l0 + mloc) = o;
      } else {
        unsigned short* dst = (part ? kg : qg) + (((size_t)(b*NH + hb)*LPAD) + l0 + mloc)*HD + d;
        dst[0]     = bf16c(v[0] + bias);
        dst[HD]    = bf16c(v[1] + bias);
        dst[2*HD]  = bf16c(v[2] + bias);
        dst[3*HD]  = bf16c(v[3] + bias);
      }
    }
  }
}

// ---------------------------------------------------------------- GEMM2: proj
__global__ __launch_bounds__(512, 2) void gemm_proj(
    const unsigned short* __restrict__ A, const unsigned short* __restrict__ W,
    const float* __restrict__ pbias, float* __restrict__ out)
{
  __shared__ __align__(16) unsigned short lds[65536];
  f32x4 acc[8][4] = {};
  const int bid = blockIdx.x;
  const int swz = (bid & 7)*20 + (bid >> 3);
  const int mt = swz >> 3, ntt = swz & 7;
  const int m0 = mt << 8, n0 = ntt << 8;
  gemm8p(A, W, lds, m0, n0, acc);

  const int tid = threadIdx.x;
  const int w = tid >> 6, lane = tid & 63, g = lane >> 4, lr = lane & 15;
  const int wm = w >> 2, wn = w & 3;
  const int b = (m0 >= LPAD) ? 1 : 0;
  const int l0 = m0 - b*LPAD;
#pragma unroll
  for (int i = 0; i < 8; ++i){
    const int mloc = wm*128 + i*16 + (g << 2);
#pragma unroll
    for (int j = 0; j < 4; ++j){
      const int n = n0 + wn*64 + j*16 + lr;
      const float bias = pbias[n];
      const f32x4 v = acc[i][j];
#pragma unroll
      for (int r = 0; r < 4; ++r){
        const int l = l0 + mloc + r;
        if (l < SEQL) out[(((size_t)(b*SEQL + l)) << 11) + n] = v[r] + bias;
      }
    }
  }
}

// ---------------------------------------------------------------- rope + norm
__global__ __launch_bounds__(256) void rope_norm(
    unsigned short* __restrict__ qg, unsigned short* __restrict__ kg,
    const float* __restrict__ rope, const float* __restrict__ smlog)
{
  const int sub = threadIdx.x & 15;
  const int l = blockIdx.x*16 + (threadIdx.x >> 4);
  if (l >= SEQL) return;
  const int pb = blockIdx.y;
  const int part = pb >> 5, bh = pb & 31, h = bh & 15;
  unsigned short* base = (part ? kg : qg) + ((long)bh*LPAD + l)*HD + (sub << 3);
  const u16x8 v = *(const u16x8*)base;
  float f[8];
#pragma unroll
  for (int i = 0; i < 8; ++i) f[i] = bf2f(v[i]);
  float ss = 0.f;
#pragma unroll
  for (int i = 0; i < 8; ++i) ss += f[i]*f[i];
  ss += __shfl_xor(ss, 1, 16);
  ss += __shfl_xor(ss, 2, 16);
  ss += __shfl_xor(ss, 4, 16);
  ss += __shfl_xor(ss, 8, 16);
  float inv = 1.f / fmaxf(sqrtf(ss), 1e-12f);
  if (part == 0){
    float sl = fminf(smlog[h], 4.605170185988091f);
    inv *= __expf(sl) * 1.4426950408889634f;          // fold log2(e)
  }
  const float4 cs = *(const float4*)(rope + (long)l*64 + (sub << 2));
  const float4 sn = *(const float4*)(rope + (long)(SEQL + l)*64 + (sub << 2));
  u16x8 o;
  const float c4[4] = {cs.x, cs.y, cs.z, cs.w};
  const float s4[4] = {sn.x, sn.y, sn.z, sn.w};
#pragma unroll
  for (int p = 0; p < 4; ++p){
    const float re = f[2*p], im = f[2*p+1];
    o[2*p]   = bf16c((c4[p]*re - s4[p]*im)*inv);
    o[2*p+1] = bf16c((s4[p]*re + c4[p]*im)*inv);
  }
  *(u16x8*)base = o;
}

// ---------------------------------------------------------------- attention
static __device__ __forceinline__ int q_end_of(int q){
  if (q >= SEQL) return 1;
  if (q < 121){
    if (q < 1) return 1;
    if (q < 5) return 5;
    if (q < 21) return 21;
    if (q < 57) return 57;
    return 121;
  }
  if (q < 265) return 265;
  if (q < 521) return 521;
  if (q < 921) return 921;
  if (q < 1497) return 1497;
  return 2521;
}

// 4 waves x 32 q-rows = 128 q-rows per block; KV tile 64; K LDS dbuf, V direct global.
// Grid: 1-D, bh = bid&31 -> bid%8 = bh%8 (XCD-clustered KV reuse), qt = 19-(bid>>5).
__global__ __launch_bounds__(256, 2) void attn_kernel(
    const unsigned short* __restrict__ qg, const unsigned short* __restrict__ kg,
    const unsigned short* __restrict__ vt, unsigned short* __restrict__ aout)
{
  __shared__ __align__(16) unsigned short Ks[2*64*128];  // [buf][kv][hd], chunk^f_K(kv)
  const int tid = threadIdx.x, w = tid >> 6, lane = tid & 63;
  const int g = lane >> 4, lr = lane & 15, lr7 = lr & 7;
  const int bid = blockIdx.x;
  const int bh = bid & 31;
  const int qt = 19 - (bid >> 5);                        // longest first
  const int q0 = qt << 7, qw = q0 + (w << 5);            // wave owns 32 q-rows
  const long kvBase = (long)bh * LPAD * HD;

  u16x8 qfA[4], qfB[4];
  {
    const unsigned short* qrow = qg + kvBase + (long)(qw + lr)*HD + (g << 3);
#pragma unroll
    for (int c = 0; c < 4; ++c) qfA[c] = *(const u16x8*)(qrow + (c << 5));
    const unsigned short* qrow2 = qrow + (long)16*HD;
#pragma unroll
    for (int c = 0; c < 4; ++c) qfB[c] = *(const u16x8*)(qrow2 + (c << 5));
  }
  const int qeA = q_end_of(qw + lr);
  const int qeB = q_end_of(qw + 16 + lr);
  const int qe0 = q_end_of(qw);                          // min over wave
  const int qmax = (q0 + 127 < SEQL - 1) ? q0 + 127 : SEQL - 1;
  const int nt = (q_end_of(qmax) + 63) >> 6;

  float m2A = -1e30f, lA = 0.f, m2B = -1e30f, lB = 0.f;
  f32x4 oA[8] = {}, oB[8] = {};

  // V base for this lane: row d = nf*16 + lr, col = kvb + (c*4+g)*8
  const unsigned short* vbase = vt + kvBase + (size_t)lr*LPAD + (g << 3);

  auto stageK = [&](int t, int buf){
    const int kvb2 = t << 6;
#pragma unroll
    for (int c = 0; c < 4; ++c){
      const int cb = (c << 8) + tid;                     // 0..1023 K chunks
      const int row = cb >> 4, cc = cb & 15;
      const int fk = (row & 3) | (((row >> 3) & 1) << 2);
      const int sc = (cc & 8) | ((cc & 7) ^ fk);
      glds16(kg + kvBase + (size_t)(kvb2 + row)*HD + (sc << 3),
             Ks + buf*8192 + (((c << 8) + (w << 6)) << 3));
    }
  };

  stageK(0, 0);

  for (int t = 0; t < nt; ++t){
    __builtin_amdgcn_s_barrier();                        // all waves done reading buf[t-1]
    const bool pf = (t + 1 < nt);
    if (pf){
      stageK(t + 1, (t + 1) & 1);
      asm volatile("s_waitcnt vmcnt(4)" ::: "memory");   // tile t resident (own 4 chunks)
    } else {
      asm volatile("s_waitcnt vmcnt(0)" ::: "memory");
    }
    __builtin_amdgcn_s_barrier();                        // all waves' chunks landed

    const unsigned short* Kb = Ks + (t & 1)*8192;
    const int kvb = t << 6;

    // ---- QK^T (permuted K rows) ----
    f32x4 sA[4] = {}, sB[4] = {};
    __builtin_amdgcn_s_setprio(1);
#pragma unroll
    for (int mf = 0; mf < 4; ++mf){
      const int kvr = ((mf & 1) << 2) + ((mf >> 1) << 5) + ((lr >> 2) << 3) + (lr & 3);
      const unsigned short* kr = Kb + kvr*HD;
#pragma unroll
      for (int c = 0; c < 4; ++c){
        const int cc = (c << 2) + g;
        const int swz = (cc & 8) | ((cc & 7) ^ lr7);
        const u16x8 kf = *(const u16x8*)(kr + (swz << 3));
        sA[mf] = __builtin_amdgcn_mfma_f32_16x16x32_bf16(asbf(kf), asbf(qfA[c]), sA[mf], 0, 0, 0);
        sB[mf] = __builtin_amdgcn_mfma_f32_16x16x32_bf16(asbf(kf), asbf(qfB[c]), sB[mf], 0, 0, 0);
      }
    }
    __builtin_amdgcn_s_setprio(0);

    const bool fullvis = (kvb + 64 <= qe0);

#define SM_STEP(SS, M2, LL, OO, QEL, ALPHA) { \
    float tmax = -1e30f; \
    if (fullvis){ \
      _Pragma("unroll") for (int mf = 0; mf < 4; ++mf) \
        _Pragma("unroll") for (int r = 0; r < 4; ++r) tmax = fmaxf(tmax, SS[mf][r]); \
    } else { \
      _Pragma("unroll") for (int mf = 0; mf < 4; ++mf){ \
        _Pragma("unroll") for (int r = 0; r < 4; ++r){ \
          const int kvg = kvb + (g << 3) + ((mf & 1) << 2) + r + ((mf >> 1) << 5); \
          float s_ = (kvg < QEL) ? SS[mf][r] : -1e30f; \
          SS[mf][r] = s_; tmax = fmaxf(tmax, s_); \
        } \
      } \
    } \
    tmax = fmaxf(tmax, __shfl_xor(tmax, 16, 64)); \
    tmax = fmaxf(tmax, __shfl_xor(tmax, 32, 64)); \
    float ALPHA = 1.f; \
    if (!__all(tmax <= M2 + 11.0f)){ \
      const float mnew = fmaxf(M2, tmax); \
      ALPHA = exp2f(M2 - mnew); M2 = mnew; \
      const float a0 = __shfl(ALPHA, (g << 2) + 0, 64); \
      const float a1 = __shfl(ALPHA, (g << 2) + 1, 64); \
      const float a2 = __shfl(ALPHA, (g << 2) + 2, 64); \
      const float a3 = __shfl(ALPHA, (g << 2) + 3, 64); \
      _Pragma("unroll") for (int nf = 0; nf < 8; ++nf){ \
        OO[nf][0] *= a0; OO[nf][1] *= a1; OO[nf][2] *= a2; OO[nf][3] *= a3; \
      } \
    } \
    float ts = 0.f; \
    _Pragma("unroll") for (int mf = 0; mf < 4; ++mf){ \
      _Pragma("unroll") for (int r = 0; r < 4; ++r){ \
        const float p_ = exp2f(SS[mf][r] - M2); SS[mf][r] = p_; ts += p_; \
      } \
    } \
    ts += __shfl_xor(ts, 16, 64); \
    ts += __shfl_xor(ts, 32, 64); \
    LL = LL*ALPHA + ts; }

    SM_STEP(sA, m2A, lA, oA, qeA, alphaA)
    SM_STEP(sB, m2B, lB, oB, qeB, alphaB)
#undef SM_STEP

    // ---- pack P in-register ----
    u16x8 paA[2], paB[2];
#pragma unroll
    for (int c = 0; c < 2; ++c){
#pragma unroll
      for (int r = 0; r < 4; ++r){
        paA[c][r]   = bf16c(sA[2*c][r]);
        paA[c][4+r] = bf16c(sA[2*c+1][r]);
        paB[c][r]   = bf16c(sB[2*c][r]);
        paB[c][4+r] = bf16c(sB[2*c+1][r]);
      }
    }

    // ---- O += P * V (V fragments direct from global, L2-hot) ----
    __builtin_amdgcn_s_setprio(1);
#pragma unroll
    for (int c = 0; c < 2; ++c){
#pragma unroll
      for (int nf = 0; nf < 8; ++nf){
        const u16x8 vf = *(const u16x8*)(vbase + (size_t)(nf << 4)*LPAD + kvb + (c << 5));
        oA[nf] = __builtin_amdgcn_mfma_f32_16x16x32_bf16(asbf(paA[c]), asbf(vf), oA[nf], 0, 0, 0);
        oB[nf] = __builtin_amdgcn_mfma_f32_16x16x32_bf16(asbf(paB[c]), asbf(vf), oB[nf], 0, 0, 0);
      }
    }
    __builtin_amdgcn_s_setprio(0);
  }

  const int b = bh >> 4, h = bh & 15;
  {
    const float rcp = 1.f / lA;
    const float li0 = __shfl(rcp, (g << 2) + 0, 64);
    const float li1 = __shfl(rcp, (g << 2) + 1, 64);
    const float li2 = __shfl(rcp, (g << 2) + 2, 64);
    const float li3 = __shfl(rcp, (g << 2) + 3, 64);
#pragma unroll
    for (int r = 0; r < 4; ++r){
      const int qq = qw + (g << 2) + r;
      if (qq < SEQL){
        const float lir = (r == 0) ? li0 : ((r == 1) ? li1 : ((r == 2) ? li2 : li3));
        unsigned short* dst = aout + (((long)(b*LPAD + qq)) << 11) + (h << 7) + lr;
#pragma unroll
        for (int nf = 0; nf < 8; ++nf)
          dst[nf << 4] = bf16c(oA[nf][r] * lir);
      }
    }
  }
  {
    const float rcp = 1.f / lB;
    const float li0 = __shfl(rcp, (g << 2) + 0, 64);
    const float li1 = __shfl(rcp, (g << 2) + 1, 64);
    const float li2 = __shfl(rcp, (g << 2) + 2, 64);
    const float li3 = __shfl(rcp, (g << 2) + 3, 64);
#pragma unroll
    for (int r = 0; r < 4; ++r){
      const int qq = qw + 16 + (g << 2) + r;
      if (qq < SEQL){
        const float lir = (r == 0) ? li0 : ((r == 1) ? li1 : ((r == 2) ? li2 : li3));
        unsigned short* dst = aout + (((long)(b*LPAD + qq)) << 11) + (h << 7) + lr;
#pragma unroll
        for (int nf = 0; nf < 8; ++nf)
          dst[nf << 4] = bf16c(oB[nf][r] * lir);
      }
    }
  }
}

// ---------------------------------------------------------------- launch
extern "C" void kernel_launch(void* const* d_in, const int* in_sizes, int n_in,
                              void* d_out, int out_size, void* d_ws, size_t ws_size,
                              hipStream_t stream) {
  const float* x     = (const float*)d_in[0];
  const float* wqkv  = (const float*)d_in[1];
  const float* qb    = (const float*)d_in[2];
  const float* vb    = (const float*)d_in[3];
  const float* smlog = (const float*)d_in[4];
  const float* projw = (const float*)d_in[5];
  const float* projb = (const float*)d_in[6];
  const float* rope  = (const float*)d_in[7];
  float* out = (float*)d_out;

  unsigned short* xb = (unsigned short*)d_ws;
  unsigned short* wb = xb + (size_t)NB*LPAD*CD;
  unsigned short* pw = wb + (size_t)3*CD*CD;
  unsigned short* qg = pw + (size_t)CD*CD;
  unsigned short* kg = qg + (size_t)NB*NH*LPAD*HD;
  unsigned short* vt = kg + (size_t)NB*NH*LPAD*HD;

  prep_kernel<<<2048, 256, 0, stream>>>(x, wqkv, projw, xb, wb, pw);
  gemm_qkv<<<480, 512, 0, stream>>>(xb, wb, qb, vb, qg, kg, vt);
  rope_norm<<<dim3(158, 64), 256, 0, stream>>>(qg, kg, rope, smlog);
  attn_kernel<<<640, 256, 0, stream>>>(qg, kg, vt, xb);
  gemm_proj<<<160, 512, 0, stream>>>(xb, pw, projb, out);
}